// Round 15
// baseline (227.568 us; speedup 1.0000x reference)
//
#include <hip/hip_runtime.h>

// ConnectivityLoss R15: border-specialized sweep (no new work, less issued).
//  - hpool<MN,LRB>: fix cndmasks compile out for the 85% of blocks not
//    touching image cols 0/511 (block-uniform dispatch, barrier-safe).
//  - vfT/vfB ternary sites behind wave-uniform branches: ~94% of waves issue
//    the clean path.
//  - it-loop unroll 1 (R14: full unroll neutral) to keep 2x template code
//    small for I-cache.
// EMPIRICAL RULES (R5/R7/R8/R9/R13):
//  - launch_bounds stays (256,3); (256,4) => 64-VGPR target => 1.4 GB scratch.
//  - f16 stash regressed (R13: allocator dropped to 64 VGPR, -10%).
//  - One atomic per BLOCK (per-wave atomics serialize cross-XCD, +100us).
//  - Tripwire: WRITE_SIZE must stay ~52 B (spills show up here first).

#define IMG 512
#define OC  40            // output cols per tile (13 x-tiles; last partial)
#define TH  128           // output rows per tile (4 y-tiles)
#define TPI 52            // tiles per image = 13 * 4
#define SKW 42            // skeleton stash cols [11,52]
#define SKH 130           // skeleton stash rows [11,140]
#define XR   68           // exchange row stride (floats)
#define XSLOT (4*XR)      // 4 rows per wave: {A0,A1,A3,A4}
#define XHALF (4*XSLOT)   // 4 waves
#define NT  256

struct alignas(16) R8 { float v[8]; };

__device__ __forceinline__ float f3min(float a, float b, float c) {
    return fminf(fminf(a, b), c);
}
__device__ __forceinline__ float f3max(float a, float b, float c) {
    return fmaxf(fmaxf(a, b), c);
}
__device__ __forceinline__ float dpp_up1(float x) {   // lane i <- i-1
    int r = __builtin_amdgcn_update_dpp(
        0, __builtin_bit_cast(int, x), 0x111, 0xF, 0xF, true); // row_shr:1
    return __builtin_bit_cast(float, r);
}
__device__ __forceinline__ float dpp_dn1(float x) {   // lane i <- i+1
    int r = __builtin_amdgcn_update_dpp(
        0, __builtin_bit_cast(int, x), 0x101, 0xF, 0xF, true); // row_shl:1
    return __builtin_bit_cast(float, r);
}
__device__ __forceinline__ float bpermf(int addr, float x) {
    return __builtin_bit_cast(float,
        __builtin_amdgcn_ds_bpermute(addr, __builtin_bit_cast(int, x)));
}

// horizontal 3-tap; le/ri from strip s-1/s+1 (lane -8/+8). LRB=false folds
// the image-col-border fix cndmasks away entirely.
template<bool MN, bool LRB>
__device__ __forceinline__ void hpool(const R8& r, R8& h, bool fixL, bool fixR,
                                      int aL, int aR) {
    float le = bpermf(aL, r.v[7]);
    float ri = bpermf(aR, r.v[0]);
    if (MN) {
        h.v[0] = f3min(le,     r.v[0], r.v[1]);
        h.v[1] = f3min(r.v[0], r.v[1], r.v[2]);
        h.v[2] = f3min(r.v[1], r.v[2], r.v[3]);
        h.v[3] = f3min(r.v[2], r.v[3], r.v[4]);
        h.v[4] = f3min(r.v[3], r.v[4], r.v[5]);
        h.v[5] = f3min(r.v[4], r.v[5], r.v[6]);
        h.v[6] = f3min(r.v[5], r.v[6], r.v[7]);
        h.v[7] = f3min(r.v[6], r.v[7], ri);
        if (LRB) {
            if (fixL) h.v[4] = fminf(r.v[4], r.v[5]);   // gx==0
            if (fixR) h.v[3] = fminf(r.v[2], r.v[3]);   // gx==511
        }
    } else {
        h.v[0] = f3max(le,     r.v[0], r.v[1]);
        h.v[1] = f3max(r.v[0], r.v[1], r.v[2]);
        h.v[2] = f3max(r.v[1], r.v[2], r.v[3]);
        h.v[3] = f3max(r.v[2], r.v[3], r.v[4]);
        h.v[4] = f3max(r.v[3], r.v[4], r.v[5]);
        h.v[5] = f3max(r.v[4], r.v[5], r.v[6]);
        h.v[6] = f3max(r.v[5], r.v[6], r.v[7]);
        h.v[7] = f3max(r.v[6], r.v[7], ri);
        if (LRB) {
            if (fixL) h.v[4] = fmaxf(r.v[4], r.v[5]);
            if (fixR) h.v[3] = fmaxf(r.v[2], r.v[3]);
        }
    }
}

// one fused skeletonize iteration (separable min/max pooling, rolling
// w-window). Barrier inside: caller's LRB dispatch is block-uniform.
template<bool LRB>
__device__ __forceinline__ void sweep_it(R8 (&A)[5], float* __restrict__ Xb,
                                         int wv, int gq, int s, int sw,
                                         int aL, int aR,
                                         bool fixL, bool fixR,
                                         bool vwT, bool vwB)
{
    // ---- post boundary A-rows (old values) for vertical halo ----
    if (gq == 0) {
        float* p = Xb + wv * XSLOT + sw;          // rows 0,1
        *(float4*)p            = *(const float4*)&A[0].v[0];
        *(float4*)(p + 4)      = *(const float4*)&A[0].v[4];
        *(float4*)(p + XR)     = *(const float4*)&A[1].v[0];
        *(float4*)(p + XR + 4) = *(const float4*)&A[1].v[4];
    }
    if (gq == 7) {
        float* p = Xb + wv * XSLOT + 2*XR + sw;   // rows 2,3
        *(float4*)p            = *(const float4*)&A[3].v[0];
        *(float4*)(p + 4)      = *(const float4*)&A[3].v[4];
        *(float4*)(p + XR)     = *(const float4*)&A[4].v[0];
        *(float4*)(p + XR + 4) = *(const float4*)&A[4].v[4];
    }
    __syncthreads();

    // ---- vertical halo: A[-2],A[-1],A[5],A[6] ----
    R8 am2, am1, ap5, ap6;
    #pragma unroll
    for (int j = 0; j < 8; ++j) {
        am2.v[j] = dpp_up1(A[3].v[j]);   // gq-1's A[3] = my pr-2
        am1.v[j] = dpp_up1(A[4].v[j]);   // gq-1's A[4] = my pr-1
        ap5.v[j] = dpp_dn1(A[0].v[j]);   // gq+1's A[0] = my pr+5
        ap6.v[j] = dpp_dn1(A[1].v[j]);   // gq+1's A[1] = my pr+6
    }
    if (gq == 0) {
        if (wv) {
            const float* p = Xb + (wv - 1) * XSLOT + 2*XR + sw;
            *(float4*)&am2.v[0] = *(const float4*)p;
            *(float4*)&am2.v[4] = *(const float4*)(p + 4);
            *(float4*)&am1.v[0] = *(const float4*)(p + XR);
            *(float4*)&am1.v[4] = *(const float4*)(p + XR + 4);
        } else { am2 = A[0]; am1 = A[0]; }  // tile-edge garbage margin
    }
    if (gq == 7) {
        if (wv < 3) {
            const float* p = Xb + (wv + 1) * XSLOT + sw;
            *(float4*)&ap5.v[0] = *(const float4*)p;
            *(float4*)&ap5.v[4] = *(const float4*)(p + 4);
            *(float4*)&ap6.v[0] = *(const float4*)(p + XR);
            *(float4*)&ap6.v[4] = *(const float4*)(p + XR + 4);
        } else { ap5 = A[4]; ap6 = A[4]; }
    }

    // ---- fused sweep: rolling w-window (wA,wB,wC), update A[k] ----
    R8 vt, wA, wB, wC, pp, mx;
    #define VMIN3(d, x, y, z)                                                  \
        _Pragma("unroll")                                                      \
        for (int j = 0; j < 8; ++j) d.v[j] = f3min((x).v[j], (y).v[j], (z).v[j]);
    #define UPD(i, CEN)                                                        \
        _Pragma("unroll")                                                      \
        for (int j = 0; j < 8; ++j) {                                          \
            float ct = mx.v[j] - (CEN).v[j];                                   \
            A[i].v[j] = fmaxf(A[i].v[j] - ct, 0.0f);                           \
        }
    VMIN3(vt, am2, am1, A[0])                           // v[-1]
    hpool<true, LRB>(vt, wA, fixL, fixR, aL, aR);       // w[-1]
    VMIN3(vt, am1, A[0], A[1])                          // v[0]
    hpool<true, LRB>(vt, wB, fixL, fixR, aL, aR);       // w[0]
    VMIN3(vt, A[0], A[1], A[2])                         // v[1]
    hpool<true, LRB>(vt, wC, fixL, fixR, aL, aR);       // w[1]
    // k=0: window (wA,wB,wC), center wB
    #pragma unroll
    for (int j = 0; j < 8; ++j) pp.v[j] = f3max(wA.v[j], wB.v[j], wC.v[j]);
    hpool<false, LRB>(pp, mx, fixL, fixR, aL, aR);
    UPD(0, wB)
    // v[2] (vwT waves: pr 12 drops pr 11 tap = A[1]; others clean)
    if (vwT) {
        #pragma unroll
        for (int j = 0; j < 8; ++j)
            vt.v[j] = (gq == 2) ? fminf(A[2].v[j], A[3].v[j])
                                : f3min(A[1].v[j], A[2].v[j], A[3].v[j]);
    } else {
        VMIN3(vt, A[1], A[2], A[3])
    }
    hpool<true, LRB>(vt, wA, fixL, fixR, aL, aR);       // w[2]
    // k=1: window (wB,wC,wA), center wC
    #pragma unroll
    for (int j = 0; j < 8; ++j) pp.v[j] = f3max(wB.v[j], wC.v[j], wA.v[j]);
    hpool<false, LRB>(pp, mx, fixL, fixR, aL, aR);
    UPD(1, wC)
    VMIN3(vt, A[2], A[3], A[4])                         // v[3]
    hpool<true, LRB>(vt, wB, fixL, fixR, aL, aR);       // w[3]
    // k=2: window (wC,wA,wB), center wA (vwT waves drop w[1]=wC at gq 2)
    if (vwT) {
        #pragma unroll
        for (int j = 0; j < 8; ++j)
            pp.v[j] = (gq == 2) ? fmaxf(wA.v[j], wB.v[j])
                                : f3max(wC.v[j], wA.v[j], wB.v[j]);
    } else {
        #pragma unroll
        for (int j = 0; j < 8; ++j)
            pp.v[j] = f3max(wC.v[j], wA.v[j], wB.v[j]);
    }
    hpool<false, LRB>(pp, mx, fixL, fixR, aL, aR);
    UPD(2, wA)
    // v[4] (vwB waves: pr 139 drops pr 140 tap = ap5 at gq 3; others clean)
    if (vwB) {
        #pragma unroll
        for (int j = 0; j < 8; ++j)
            vt.v[j] = (gq == 3) ? fminf(A[3].v[j], A[4].v[j])
                                : f3min(A[3].v[j], A[4].v[j], ap5.v[j]);
    } else {
        VMIN3(vt, A[3], A[4], ap5)
    }
    hpool<true, LRB>(vt, wC, fixL, fixR, aL, aR);       // w[4]
    // k=3: window (wA,wB,wC), center wB
    #pragma unroll
    for (int j = 0; j < 8; ++j) pp.v[j] = f3max(wA.v[j], wB.v[j], wC.v[j]);
    hpool<false, LRB>(pp, mx, fixL, fixR, aL, aR);
    UPD(3, wB)
    VMIN3(vt, A[4], ap5, ap6)                           // v[5]
    hpool<true, LRB>(vt, wA, fixL, fixR, aL, aR);       // w[5]
    // k=4: window (wB,wC,wA), center wC (vwB waves drop w[5]=wA at gq 3)
    if (vwB) {
        #pragma unroll
        for (int j = 0; j < 8; ++j)
            pp.v[j] = (gq == 3) ? fmaxf(wB.v[j], wC.v[j])
                                : f3max(wB.v[j], wC.v[j], wA.v[j]);
    } else {
        #pragma unroll
        for (int j = 0; j < 8; ++j)
            pp.v[j] = f3max(wB.v[j], wC.v[j], wA.v[j]);
    }
    hpool<false, LRB>(pp, mx, fixL, fixR, aL, aR);
    UPD(4, wC)
    #undef VMIN3
    #undef UPD
}

__global__ __launch_bounds__(NT, 3)
void skel_conn_loss(const float* __restrict__ pred,
                    const float* __restrict__ target,
                    float* __restrict__ out)
{
    __shared__ float X[2*XHALF];         // A-halo exchange dbuf (8.7 KB)
    __shared__ float SKP[SKH*SKW];       // pred skeleton (21.8 KB)
    __shared__ float SKT[SKH*SKW];       // target skeleton
    __shared__ float red[4];

    const int tid  = threadIdx.x;
    const int wv   = tid >> 6;           // wave 0..3 owns rows 40w..40w+39
    const int lane = tid & 63;
    const int s    = lane >> 3;          // 8-col strip
    const int gq   = lane & 7;           // row group (5 rows); +-1 == lane+-1
    const int img  = blockIdx.x / TPI;
    const int rem  = blockIdx.x % TPI;
    const int ty0  = (rem / 13) * TH;
    const int tx0  = (rem % 13) * OC;

    const int c0  = 8*s;
    const int r0  = 40*wv + 5*gq;
    const int gx0 = tx0 - 12 + c0;
    const bool xin = (tx0 > 0) && (tx0 + 52 <= IMG);   // strip fully in-image

    const bool lB = (tx0 == 0), rB = (tx0 + OC >= IMG);
    const bool tB = (ty0 == 0), bB = (ty0 + TH == IMG);
    const bool lrB  = lB || rB;                      // block-uniform
    const bool fixL = lB && (s == 1);                // c 12 == gx 0
    const bool fixR = rB && (s == 5);                // c 43 == gx 511
    const bool vwT  = tB && (wv == 0);               // wave-uniform
    const bool vwB  = bB && (wv == 3);
    const int  sw   = 8*s + 4*(s >> 2);              // bank-swizzled exch col
    const int  aL   = ((lane - 8) & 63) * 4;         // bpermute addrs
    const int  aR   = ((lane + 8) & 63) * 4;

    R8 A[5];
    int xb = 0;

    #pragma unroll 1
    for (int t = 0; t < 2; ++t) {
        const float* __restrict__ src =
            (t ? target : pred) + (size_t)img * (IMG * IMG);

        // ---- load strip (addresses clamped; OOB values never consumed) ----
        #pragma unroll
        for (int i = 0; i < 5; ++i) {
            int gy = min(max(ty0 - 12 + r0 + i, 0), IMG - 1);
            const float* rp = src + gy * IMG;
            if (xin) {
                *(float4*)&A[i].v[0] = *(const float4*)(rp + gx0);
                *(float4*)&A[i].v[4] = *(const float4*)(rp + gx0 + 4);
            } else {
                #pragma unroll
                for (int j = 0; j < 8; ++j)
                    A[i].v[j] = rp[min(max(gx0 + j, 0), IMG - 1)];
            }
        }

        // ---- 5 fused iterations; LRB specialized, block-uniform ----
        if (lrB) {
            #pragma unroll 1
            for (int it = 0; it < 5; ++it) {
                sweep_it<true>(A, X + xb * XHALF, wv, gq, s, sw, aL, aR,
                               fixL, fixR, vwT, vwB);
                xb ^= 1;
            }
        } else {
            #pragma unroll 1
            for (int it = 0; it < 5; ++it) {
                sweep_it<false>(A, X + xb * XHALF, wv, gq, s, sw, aL, aR,
                                false, false, vwT, vwB);
                xb ^= 1;
            }
        }

        // ---- stash skeleton region [11,140]x[11,52] to LDS ----
        {
            float* SK = t ? SKT : SKP;
            #pragma unroll
            for (int i = 0; i < 5; ++i) {
                int pr = r0 + i;
                if (pr >= 11 && pr <= 140) {
                    #pragma unroll
                    for (int j = 0; j < 8; ++j) {
                        int pc = c0 + j;
                        if (pc >= 11 && pc <= 52)
                            SK[(pr - 11) * SKW + (pc - 11)] = A[i].v[j];
                    }
                }
            }
        }
        __syncthreads();   // stash done; X safe to reuse next t
    }

    // ---- epilogue: rolling-column sumpool3 + indicators + loss ----
    // thread = column cx (0..39), 6 row-groups of <=22. SK row k holds
    // global row ty0 + k - 1. Tile-12 cols gx>=512 masked by xv.
    const int cx  = tid % OC;
    const int rg  = tid / OC;            // 0..6 (rg==6 idle)
    float acc = 0.0f;
    if (rg < 6) {
        const int ry0 = rg * 22;
        const int cnt = min(22, TH - ry0);   // 22,22,22,22,22,18
        const int gx  = tx0 + cx;
        const float xv = (gx < IMG)     ? 1.0f : 0.0f;
        const float xl = (gx >= 1)      ? 1.0f : 0.0f;
        const float xr = (gx + 1 < IMG) ? 1.0f : 0.0f;

        auto hs = [&](const float* __restrict__ SK, int k) -> float {
            const float* p = SK + k * SKW + cx;
            return p[1] + xl * p[0] + xr * p[2];
        };

        float hp0, hp1, ht0, ht1;
        {
            float vT = ((unsigned)(ty0 + ry0 - 1) < IMG) ? 1.0f : 0.0f;
            hp0 = vT * hs(SKP, ry0);
            ht0 = vT * hs(SKT, ry0);
            hp1 = hs(SKP, ry0 + 1);
            ht1 = hs(SKT, ry0 + 1);
        }
        #pragma unroll 2
        for (int r = 0; r < cnt; ++r) {
            int k2 = ry0 + r + 2;
            float vB = ((unsigned)(ty0 + k2 - 1) < IMG) ? 1.0f : 0.0f;
            float hp2 = vB * hs(SKP, k2);
            float ht2 = vB * hs(SKT, k2);
            float pn = hp0 + hp1 + hp2;
            float tn = ht0 + ht1 + ht2;
            float ps = SKP[(ry0 + r + 1) * SKW + cx + 1];
            float ts = SKT[(ry0 + r + 1) * SKW + cx + 1];
            float pon = (ps > 0.5f) ? 1.0f : 0.0f;
            float ton = (ts > 0.5f) ? 1.0f : 0.0f;
            float pe = (pn == 2.0f) ? pon : 0.0f;
            float te = (tn == 2.0f) ? ton : 0.0f;
            float pc = (pn >= 4.0f) ? pon : 0.0f;
            float tc = (tn >= 4.0f) ? ton : 0.0f;
            float ds = ps - ts, de = pe - te, dc = pc - tc;
            acc += xv * (0.6f * ds * ds + 0.2f * (de * de + dc * dc));
            hp0 = hp1; hp1 = hp2;
            ht0 = ht1; ht1 = ht2;
        }
    }

    // ---- block reduction -> ONE atomic per block (R9: per-wave atomics
    // serialize cross-XCD, +100us) ----
    #pragma unroll
    for (int off = 32; off >= 1; off >>= 1)
        acc += __shfl_down(acc, off, 64);
    if (lane == 0) red[wv] = acc;
    __syncthreads();
    if (tid == 0) {
        float sum = red[0] + red[1] + red[2] + red[3];
        atomicAdd(out, sum * (1.0f / 8388608.0f));  // N = 32*512*512 = 2^23
    }
}

extern "C" void kernel_launch(void* const* d_in, const int* in_sizes, int n_in,
                              void* d_out, int out_size, void* d_ws, size_t ws_size,
                              hipStream_t stream) {
    const float* pred   = (const float*)d_in[0];
    const float* target = (const float*)d_in[1];
    float* out = (float*)d_out;
    hipMemsetAsync(d_out, 0, sizeof(float) * (out_size > 0 ? out_size : 1), stream);
    const int nblocks = 32 * TPI;   // 32 images x (4x13) tiles = 1664
    skel_conn_loss<<<nblocks, NT, 0, stream>>>(pred, target, out);
}

// Round 16
// 174.932 us; speedup vs baseline: 1.3009x; 1.3009x over previous
//
#include <hip/hip_runtime.h>

// ConnectivityLoss R16 == R14 (best proven: ~103.5us profiled, 84 VGPR,
// WRITE 52 B, absmax 0). R15's border-specialized sweep_it template spilled
// (WRITE 142 MB, VALUBusy 38%) — reverted.
// EMPIRICAL RULES (R5/R7/R8/R9/R13/R15):
//  - launch_bounds stays (256,3); (256,4) => 64-VGPR target => 1.4 GB scratch.
//  - ANY liveness-topology change (divergent-region temporaries R8, template
//    duplication R15, f16 stash R13) breaks the 80-84 VGPR schedule: spill
//    or tight-schedule regression. The R12/R14 form is a narrow optimum.
//  - One atomic per BLOCK (per-wave atomics serialize cross-XCD, +100us R9).
//  - Tripwire: WRITE_SIZE must stay ~52 B (spills show up here first).

#define IMG 512
#define OC  40            // output cols per tile (13 x-tiles; last partial)
#define TH  128           // output rows per tile (4 y-tiles)
#define TPI 52            // tiles per image = 13 * 4
#define SKW 42            // skeleton stash cols [11,52]
#define SKH 130           // skeleton stash rows [11,140]
#define XR   68           // exchange row stride (floats)
#define XSLOT (4*XR)      // 4 rows per wave: {A0,A1,A3,A4}
#define XHALF (4*XSLOT)   // 4 waves
#define NT  256

struct alignas(16) R8 { float v[8]; };

__device__ __forceinline__ float f3min(float a, float b, float c) {
    return fminf(fminf(a, b), c);
}
__device__ __forceinline__ float f3max(float a, float b, float c) {
    return fmaxf(fmaxf(a, b), c);
}
__device__ __forceinline__ float dpp_up1(float x) {   // lane i <- i-1
    int r = __builtin_amdgcn_update_dpp(
        0, __builtin_bit_cast(int, x), 0x111, 0xF, 0xF, true); // row_shr:1
    return __builtin_bit_cast(float, r);
}
__device__ __forceinline__ float dpp_dn1(float x) {   // lane i <- i+1
    int r = __builtin_amdgcn_update_dpp(
        0, __builtin_bit_cast(int, x), 0x101, 0xF, 0xF, true); // row_shl:1
    return __builtin_bit_cast(float, r);
}
__device__ __forceinline__ float bpermf(int addr, float x) {
    return __builtin_bit_cast(float,
        __builtin_amdgcn_ds_bpermute(addr, __builtin_bit_cast(int, x)));
}

// horizontal 3-tap on a (vertically pooled) row; le/ri from strip s-1/s+1
// (lane -8/+8). fixL/fixR: clamped-window at image cols 0/511.
template<bool MN>
__device__ __forceinline__ void hpool(const R8& r, R8& h, bool fixL, bool fixR,
                                      int aL, int aR) {
    float le = bpermf(aL, r.v[7]);
    float ri = bpermf(aR, r.v[0]);
    if (MN) {
        h.v[0] = f3min(le,     r.v[0], r.v[1]);
        h.v[1] = f3min(r.v[0], r.v[1], r.v[2]);
        h.v[2] = f3min(r.v[1], r.v[2], r.v[3]);
        h.v[3] = f3min(r.v[2], r.v[3], r.v[4]);
        h.v[4] = f3min(r.v[3], r.v[4], r.v[5]);
        h.v[5] = f3min(r.v[4], r.v[5], r.v[6]);
        h.v[6] = f3min(r.v[5], r.v[6], r.v[7]);
        h.v[7] = f3min(r.v[6], r.v[7], ri);
        if (fixL) h.v[4] = fminf(r.v[4], r.v[5]);   // gx==0: drop left tap
        if (fixR) h.v[3] = fminf(r.v[2], r.v[3]);   // gx==511: drop right tap
    } else {
        h.v[0] = f3max(le,     r.v[0], r.v[1]);
        h.v[1] = f3max(r.v[0], r.v[1], r.v[2]);
        h.v[2] = f3max(r.v[1], r.v[2], r.v[3]);
        h.v[3] = f3max(r.v[2], r.v[3], r.v[4]);
        h.v[4] = f3max(r.v[3], r.v[4], r.v[5]);
        h.v[5] = f3max(r.v[4], r.v[5], r.v[6]);
        h.v[6] = f3max(r.v[5], r.v[6], r.v[7]);
        h.v[7] = f3max(r.v[6], r.v[7], ri);
        if (fixL) h.v[4] = fmaxf(r.v[4], r.v[5]);
        if (fixR) h.v[3] = fmaxf(r.v[2], r.v[3]);
    }
}

__global__ __launch_bounds__(NT, 3)
void skel_conn_loss(const float* __restrict__ pred,
                    const float* __restrict__ target,
                    float* __restrict__ out)
{
    __shared__ float X[2*XHALF];         // A-halo exchange dbuf (8.7 KB)
    __shared__ float SKP[SKH*SKW];       // pred skeleton (21.8 KB)
    __shared__ float SKT[SKH*SKW];       // target skeleton
    __shared__ float red[4];

    const int tid  = threadIdx.x;
    const int wv   = tid >> 6;           // wave 0..3 owns rows 40w..40w+39
    const int lane = tid & 63;
    const int s    = lane >> 3;          // 8-col strip
    const int gq   = lane & 7;           // row group (5 rows); +-1 == lane+-1
    const int img  = blockIdx.x / TPI;
    const int rem  = blockIdx.x % TPI;
    const int ty0  = (rem / 13) * TH;
    const int tx0  = (rem % 13) * OC;

    const int c0  = 8*s;
    const int r0  = 40*wv + 5*gq;
    const int gx0 = tx0 - 12 + c0;
    const bool xin = (tx0 > 0) && (tx0 + 52 <= IMG);   // strip fully in-image

    const bool lB = (tx0 == 0), rB = (tx0 + OC >= IMG);
    const bool tB = (ty0 == 0), bB = (ty0 + TH == IMG);
    const bool fixL = lB && (s == 1);                // c 12 == gx 0
    const bool fixR = rB && (s == 5);                // c 43 == gx 511
    const bool vfT  = tB && (wv == 0) && (gq == 2);  // pr 12 == gy 0 (k==2)
    const bool vfB  = bB && (wv == 3) && (gq == 3);  // pr 139 == gy 511 (k==4)
    const int  sw   = 8*s + 4*(s >> 2);              // bank-swizzled exch col
    const int  aL   = ((lane - 8) & 63) * 4;         // bpermute addrs
    const int  aR   = ((lane + 8) & 63) * 4;

    R8 A[5];

    #pragma unroll 1
    for (int t = 0; t < 2; ++t) {
        const float* __restrict__ src =
            (t ? target : pred) + (size_t)img * (IMG * IMG);

        // ---- load strip (addresses clamped; OOB values never consumed) ----
        #pragma unroll
        for (int i = 0; i < 5; ++i) {
            int gy = min(max(ty0 - 12 + r0 + i, 0), IMG - 1);
            const float* rp = src + gy * IMG;
            if (xin) {
                *(float4*)&A[i].v[0] = *(const float4*)(rp + gx0);
                *(float4*)&A[i].v[4] = *(const float4*)(rp + gx0 + 4);
            } else {
                #pragma unroll
                for (int j = 0; j < 8; ++j)
                    A[i].v[j] = rp[min(max(gx0 + j, 0), IMG - 1)];
            }
        }

        // FULL unroll: xb and exchange base fold to compile-time constants.
        #pragma unroll
        for (int it = 0; it < 5; ++it) {
            float* Xb = X + (it & 1) * XHALF;
            // ---- post boundary A-rows (old values) for vertical halo ----
            if (gq == 0) {
                float* p = Xb + wv * XSLOT + sw;          // rows 0,1
                *(float4*)p            = *(const float4*)&A[0].v[0];
                *(float4*)(p + 4)      = *(const float4*)&A[0].v[4];
                *(float4*)(p + XR)     = *(const float4*)&A[1].v[0];
                *(float4*)(p + XR + 4) = *(const float4*)&A[1].v[4];
            }
            if (gq == 7) {
                float* p = Xb + wv * XSLOT + 2*XR + sw;   // rows 2,3
                *(float4*)p            = *(const float4*)&A[3].v[0];
                *(float4*)(p + 4)      = *(const float4*)&A[3].v[4];
                *(float4*)(p + XR)     = *(const float4*)&A[4].v[0];
                *(float4*)(p + XR + 4) = *(const float4*)&A[4].v[4];
            }
            __syncthreads();

            // ---- vertical halo: A[-2],A[-1],A[5],A[6] ----
            R8 am2, am1, ap5, ap6;
            #pragma unroll
            for (int j = 0; j < 8; ++j) {
                am2.v[j] = dpp_up1(A[3].v[j]);   // gq-1's A[3] = my pr-2
                am1.v[j] = dpp_up1(A[4].v[j]);   // gq-1's A[4] = my pr-1
                ap5.v[j] = dpp_dn1(A[0].v[j]);   // gq+1's A[0] = my pr+5
                ap6.v[j] = dpp_dn1(A[1].v[j]);   // gq+1's A[1] = my pr+6
            }
            if (gq == 0) {
                if (wv) {
                    const float* p = Xb + (wv - 1) * XSLOT + 2*XR + sw;
                    *(float4*)&am2.v[0] = *(const float4*)p;
                    *(float4*)&am2.v[4] = *(const float4*)(p + 4);
                    *(float4*)&am1.v[0] = *(const float4*)(p + XR);
                    *(float4*)&am1.v[4] = *(const float4*)(p + XR + 4);
                } else { am2 = A[0]; am1 = A[0]; }  // tile-edge garbage margin
            }
            if (gq == 7) {
                if (wv < 3) {
                    const float* p = Xb + (wv + 1) * XSLOT + sw;
                    *(float4*)&ap5.v[0] = *(const float4*)p;
                    *(float4*)&ap5.v[4] = *(const float4*)(p + 4);
                    *(float4*)&ap6.v[0] = *(const float4*)(p + XR);
                    *(float4*)&ap6.v[4] = *(const float4*)(p + XR + 4);
                } else { ap5 = A[4]; ap6 = A[4]; }
            }

            // ---- fused sweep: rolling w-window (wA,wB,wC), update A[k] ----
            R8 vt, wA, wB, wC, pp, mx;
            #define VMIN3(d, x, y, z)                                          \
                _Pragma("unroll")                                              \
                for (int j = 0; j < 8; ++j) d.v[j] = f3min((x).v[j], (y).v[j], (z).v[j]);
            #define UPD(i, CEN)                                                \
                _Pragma("unroll")                                              \
                for (int j = 0; j < 8; ++j) {                                  \
                    float ct = mx.v[j] - (CEN).v[j];                           \
                    A[i].v[j] = fmaxf(A[i].v[j] - ct, 0.0f);                   \
                }
            VMIN3(vt, am2, am1, A[0])                     // v[-1]
            hpool<true>(vt, wA, fixL, fixR, aL, aR);      // w[-1]
            VMIN3(vt, am1, A[0], A[1])                    // v[0]
            hpool<true>(vt, wB, fixL, fixR, aL, aR);      // w[0]
            VMIN3(vt, A[0], A[1], A[2])                   // v[1]
            hpool<true>(vt, wC, fixL, fixR, aL, aR);      // w[1]
            // k=0: window (wA,wB,wC), center wB
            #pragma unroll
            for (int j = 0; j < 8; ++j) pp.v[j] = f3max(wA.v[j], wB.v[j], wC.v[j]);
            hpool<false>(pp, mx, fixL, fixR, aL, aR);
            UPD(0, wB)
            // v[2] -> wA (vfT: pr 12 drops pr 11 tap = A[1])
            #pragma unroll
            for (int j = 0; j < 8; ++j)
                vt.v[j] = vfT ? fminf(A[2].v[j], A[3].v[j])
                              : f3min(A[1].v[j], A[2].v[j], A[3].v[j]);
            hpool<true>(vt, wA, fixL, fixR, aL, aR);      // w[2]
            // k=1: window (wB,wC,wA), center wC
            #pragma unroll
            for (int j = 0; j < 8; ++j) pp.v[j] = f3max(wB.v[j], wC.v[j], wA.v[j]);
            hpool<false>(pp, mx, fixL, fixR, aL, aR);
            UPD(1, wC)
            VMIN3(vt, A[2], A[3], A[4])                   // v[3]
            hpool<true>(vt, wB, fixL, fixR, aL, aR);      // w[3]
            // k=2: window (wC,wA,wB), center wA; vfT drops w[1]=wC
            #pragma unroll
            for (int j = 0; j < 8; ++j)
                pp.v[j] = vfT ? fmaxf(wA.v[j], wB.v[j])
                              : f3max(wC.v[j], wA.v[j], wB.v[j]);
            hpool<false>(pp, mx, fixL, fixR, aL, aR);
            UPD(2, wA)
            // v[4] -> wC (vfB: pr 139 drops pr 140 tap = ap5)
            #pragma unroll
            for (int j = 0; j < 8; ++j)
                vt.v[j] = vfB ? fminf(A[3].v[j], A[4].v[j])
                              : f3min(A[3].v[j], A[4].v[j], ap5.v[j]);
            hpool<true>(vt, wC, fixL, fixR, aL, aR);      // w[4]
            // k=3: window (wA,wB,wC), center wB
            #pragma unroll
            for (int j = 0; j < 8; ++j) pp.v[j] = f3max(wA.v[j], wB.v[j], wC.v[j]);
            hpool<false>(pp, mx, fixL, fixR, aL, aR);
            UPD(3, wB)
            VMIN3(vt, A[4], ap5, ap6)                     // v[5]
            hpool<true>(vt, wA, fixL, fixR, aL, aR);      // w[5]
            // k=4: window (wB,wC,wA), center wC; vfB drops w[5]=wA
            #pragma unroll
            for (int j = 0; j < 8; ++j)
                pp.v[j] = vfB ? fmaxf(wB.v[j], wC.v[j])
                              : f3max(wB.v[j], wC.v[j], wA.v[j]);
            hpool<false>(pp, mx, fixL, fixR, aL, aR);
            UPD(4, wC)
            #undef VMIN3
            #undef UPD
        }

        // ---- stash skeleton region [11,140]x[11,52] to LDS ----
        {
            float* SK = t ? SKT : SKP;
            #pragma unroll
            for (int i = 0; i < 5; ++i) {
                int pr = r0 + i;
                if (pr >= 11 && pr <= 140) {
                    #pragma unroll
                    for (int j = 0; j < 8; ++j) {
                        int pc = c0 + j;
                        if (pc >= 11 && pc <= 52)
                            SK[(pr - 11) * SKW + (pc - 11)] = A[i].v[j];
                    }
                }
            }
        }
        __syncthreads();   // stash done; X safe to reuse next t
    }

    // ---- epilogue: rolling-column sumpool3 + indicators + loss ----
    // thread = column cx (0..39), 6 row-groups of <=22. SK row k holds
    // global row ty0 + k - 1. Tile-12 cols gx>=512 masked by xv.
    const int cx  = tid % OC;
    const int rg  = tid / OC;            // 0..6 (rg==6 idle)
    float acc = 0.0f;
    if (rg < 6) {
        const int ry0 = rg * 22;
        const int cnt = min(22, TH - ry0);   // 22,22,22,22,22,18
        const int gx  = tx0 + cx;
        const float xv = (gx < IMG)     ? 1.0f : 0.0f;
        const float xl = (gx >= 1)      ? 1.0f : 0.0f;
        const float xr = (gx + 1 < IMG) ? 1.0f : 0.0f;

        auto hs = [&](const float* __restrict__ SK, int k) -> float {
            const float* p = SK + k * SKW + cx;
            return p[1] + xl * p[0] + xr * p[2];
        };

        float hp0, hp1, ht0, ht1;
        {
            float vT = ((unsigned)(ty0 + ry0 - 1) < IMG) ? 1.0f : 0.0f;
            hp0 = vT * hs(SKP, ry0);
            ht0 = vT * hs(SKT, ry0);
            hp1 = hs(SKP, ry0 + 1);
            ht1 = hs(SKT, ry0 + 1);
        }
        #pragma unroll 2
        for (int r = 0; r < cnt; ++r) {
            int k2 = ry0 + r + 2;
            float vB = ((unsigned)(ty0 + k2 - 1) < IMG) ? 1.0f : 0.0f;
            float hp2 = vB * hs(SKP, k2);
            float ht2 = vB * hs(SKT, k2);
            float pn = hp0 + hp1 + hp2;
            float tn = ht0 + ht1 + ht2;
            float ps = SKP[(ry0 + r + 1) * SKW + cx + 1];
            float ts = SKT[(ry0 + r + 1) * SKW + cx + 1];
            float pon = (ps > 0.5f) ? 1.0f : 0.0f;
            float ton = (ts > 0.5f) ? 1.0f : 0.0f;
            float pe = (pn == 2.0f) ? pon : 0.0f;
            float te = (tn == 2.0f) ? ton : 0.0f;
            float pc = (pn >= 4.0f) ? pon : 0.0f;
            float tc = (tn >= 4.0f) ? ton : 0.0f;
            float ds = ps - ts, de = pe - te, dc = pc - tc;
            acc += xv * (0.6f * ds * ds + 0.2f * (de * de + dc * dc));
            hp0 = hp1; hp1 = hp2;
            ht0 = ht1; ht1 = ht2;
        }
    }

    // ---- block reduction -> ONE atomic per block (R9: per-wave atomics
    // serialize cross-XCD, +100us) ----
    #pragma unroll
    for (int off = 32; off >= 1; off >>= 1)
        acc += __shfl_down(acc, off, 64);
    if (lane == 0) red[wv] = acc;
    __syncthreads();
    if (tid == 0) {
        float sum = red[0] + red[1] + red[2] + red[3];
        atomicAdd(out, sum * (1.0f / 8388608.0f));  // N = 32*512*512 = 2^23
    }
}

extern "C" void kernel_launch(void* const* d_in, const int* in_sizes, int n_in,
                              void* d_out, int out_size, void* d_ws, size_t ws_size,
                              hipStream_t stream) {
    const float* pred   = (const float*)d_in[0];
    const float* target = (const float*)d_in[1];
    float* out = (float*)d_out;
    hipMemsetAsync(d_out, 0, sizeof(float) * (out_size > 0 ? out_size : 1), stream);
    const int nblocks = 32 * TPI;   // 32 images x (4x13) tiles = 1664
    skel_conn_loss<<<nblocks, NT, 0, stream>>>(pred, target, out);
}